// Round 2
// baseline (71679.486 us; speedup 1.0000x reference)
//
#include <hip/hip_runtime.h>
#include <math.h>

// DenseLSTMForecast: B=256, T=1024, H=128, FUTURE=32.
// Design: 128 persistent WGs x 512 threads, each WG owns 2 batch rows for all
// 1056 steps. Autoregressive feedback is row-local -> no data exchange between
// WGs. Weights pre-transposed k-major [128][512] in d_ws.
//
// R2 change: once-per-step global PHASE-LOCK barrier. R1 counters showed 78 GB
// of L2-miss traffic (47x the 1.57 MB weight set per step): unsynchronized WGs
// drift out of phase and evict each other's streaming lines. The barrier is
// purely a performance device (no data crosses it, so no fences): a monotonic
// device-scope atomic counter; polling uses fetch_add(0) RMWs which execute at
// the coherence point, so no stale-L2 deadlock risk.

#define TSEQ 1024
#define HH   128
#define TT   1056          // T + FUTURE
#define G4   512           // 4*H gate columns
#define ROWS 2
#define NWG  128

// ws float layout:
//   0*65536 : WT1  [k][g] = W_hh1[g][k]
//   1*65536 : W2a  [k][g] = W_ih2[g][1+k]     (h1 part)
//   2*65536 : W2b  [k][g] = W_hh2[g][k]
//   3*65536 : W3a  [k][g] = W_ih3[g][1+k]     (h1 part)
//   4*65536 : W3b  [k][g] = W_ih3[g][129+k]   (h2 part)
//   5*65536 : W3c  [k][g] = W_hh3[g][k]
//   6*65536 +    0 : xw1[512], +512: xw2[512], +1024: xw3[512]
//   6*65536 + 1536 : bs1[512], +2048: bs2[512], +2560: bs3[512]
//   6*65536 + 3072 : barrier counter (uint32) + padding (64 floats, zeroed)
#define WOFF_SCAL (6*65536)
#define WOFF_BAR  (6*65536 + 3072)
#define WS_FLOATS (6*65536 + 3072 + 64)

__device__ __forceinline__ float sigmoidf_(float v) {
  return 1.0f / (1.0f + expf(-v));
}

#define LOAD16(dst, srcp) do { \
  const float4* _s = (const float4*)(srcp); \
  float4 _a = _s[0], _b = _s[1], _c = _s[2], _d = _s[3]; \
  (dst)[0]=_a.x; (dst)[1]=_a.y; (dst)[2]=_a.z; (dst)[3]=_a.w; \
  (dst)[4]=_b.x; (dst)[5]=_b.y; (dst)[6]=_b.z; (dst)[7]=_b.w; \
  (dst)[8]=_c.x; (dst)[9]=_c.y; (dst)[10]=_c.z; (dst)[11]=_c.w; \
  (dst)[12]=_d.x; (dst)[13]=_d.y; (dst)[14]=_d.z; (dst)[15]=_d.w; \
} while (0)

#define LOAD8(dst, srcp) do { \
  const float4* _s = (const float4*)(srcp); \
  float4 _a = _s[0], _b = _s[1]; \
  (dst)[0]=_a.x; (dst)[1]=_a.y; (dst)[2]=_a.z; (dst)[3]=_a.w; \
  (dst)[4]=_b.x; (dst)[5]=_b.y; (dst)[6]=_b.z; (dst)[7]=_b.w; \
} while (0)

__global__ void prep_kernel(const float* __restrict__ Wih1, const float* __restrict__ Whh1,
                            const float* __restrict__ bih1, const float* __restrict__ bhh1,
                            const float* __restrict__ Wih2, const float* __restrict__ Whh2,
                            const float* __restrict__ bih2, const float* __restrict__ bhh2,
                            const float* __restrict__ Wih3, const float* __restrict__ Whh3,
                            const float* __restrict__ bih3, const float* __restrict__ bhh3,
                            float* __restrict__ ws) {
  int idx = blockIdx.x * 256 + threadIdx.x;
  if (idx < 6 * 65536) {
    int m = idx >> 16;
    int rem = idx & 65535;
    int k = rem >> 9;        // 0..127
    int g = rem & 511;       // 0..511
    float v;
    switch (m) {
      case 0:  v = Whh1[g * HH + k];         break;
      case 1:  v = Wih2[g * 129 + 1 + k];    break;
      case 2:  v = Whh2[g * HH + k];         break;
      case 3:  v = Wih3[g * 257 + 1 + k];    break;
      case 4:  v = Wih3[g * 257 + 129 + k];  break;
      default: v = Whh3[g * HH + k];         break;
    }
    ws[idx] = v;
  } else if (idx < WOFF_BAR) {
    int r = idx - WOFF_SCAL;
    float v;
    if      (r < 512)  v = Wih1[r];                        // x column, cell1
    else if (r < 1024) v = Wih2[(r - 512) * 129];          // x column, cell2
    else if (r < 1536) v = Wih3[(r - 1024) * 257];         // x column, cell3
    else if (r < 2048) v = bih1[r - 1536] + bhh1[r - 1536];
    else if (r < 2560) v = bih2[r - 2048] + bhh2[r - 2048];
    else               v = bih3[r - 2560] + bhh3[r - 2560];
    ws[idx] = v;
  } else if (idx < WS_FLOATS) {
    ws[idx] = 0.0f;          // zero the barrier counter region (ws is 0xAA-poisoned)
  }
}

__global__ __launch_bounds__(512, 1)
void lstm_kernel(const float* __restrict__ x,
                 const float* __restrict__ Wlin,
                 const float* __restrict__ blin,
                 const float* __restrict__ ws,
                 unsigned int* __restrict__ bar,
                 float* __restrict__ out) {
  __shared__ __align__(16) float h1s[ROWS][HH];
  __shared__ __align__(16) float h2s[ROWS][HH];
  __shared__ __align__(16) float h3s[ROWS][HH];
  __shared__ float gs[ROWS][G4];
  __shared__ float xs[ROWS];
  __shared__ float wl[3 * HH + 2];   // [0]=x coef, [1..384]=h coefs, [385]=b_lin

  const int tid = threadIdx.x;
  const int r0 = blockIdx.x * ROWS;

  for (int i = tid; i < ROWS * HH; i += 512) {
    (&h1s[0][0])[i] = 0.f;
    (&h2s[0][0])[i] = 0.f;
    (&h3s[0][0])[i] = 0.f;
  }
  for (int i = tid; i < 3 * HH + 2; i += 512)
    wl[i] = (i < 3 * HH + 1) ? Wlin[i] : blin[0];
  if (tid < ROWS) xs[tid] = x[(r0 + tid) * TSEQ];
  __syncthreads();

  const float* __restrict__ WT1 = ws + 0 * 65536 + tid;
  const float* __restrict__ W2a = ws + 1 * 65536 + tid;
  const float* __restrict__ W2b = ws + 2 * 65536 + tid;
  const float* __restrict__ W3a = ws + 3 * 65536 + tid;
  const float* __restrict__ W3b = ws + 4 * 65536 + tid;
  const float* __restrict__ W3c = ws + 5 * 65536 + tid;
  const float xw1 = ws[WOFF_SCAL + tid];
  const float xw2 = ws[WOFF_SCAL + 512 + tid];
  const float xw3 = ws[WOFF_SCAL + 1024 + tid];
  const float bs1 = ws[WOFF_SCAL + 1536 + tid];
  const float bs2 = ws[WOFF_SCAL + 2048 + tid];
  const float bs3 = ws[WOFF_SCAL + 2560 + tid];

  float c1 = 0.f, c2 = 0.f, c3 = 0.f;          // used by tid < 256
  const int ar = tid >> 7, aj = tid & (HH - 1);
  const int wid = tid >> 6, lane = tid & 63;

  for (int t = 0; t < TT; ++t) {
    const float x0 = xs[0];
    const float x1 = xs[1];

    // ---------------- cell 1 gates: K = 128 (h1) ----------------
    {
      float a0 = fmaf(xw1, x0, bs1);
      float a1 = fmaf(xw1, x1, bs1);
      #pragma unroll
      for (int kc = 0; kc < HH; kc += 16) {
        float ha[16], hb[16];
        LOAD16(ha, &h1s[0][kc]);
        LOAD16(hb, &h1s[1][kc]);
        #pragma unroll
        for (int j = 0; j < 16; ++j) {
          const float w = WT1[(kc + j) << 9];
          a0 = fmaf(w, ha[j], a0);
          a1 = fmaf(w, hb[j], a1);
        }
      }
      gs[0][tid] = a0;
      gs[1][tid] = a1;
    }
    __syncthreads();
    if (tid < ROWS * HH) {
      const float gi = gs[ar][aj];
      const float gf = gs[ar][aj + HH];
      const float gg = gs[ar][aj + 2 * HH];
      const float go = gs[ar][aj + 3 * HH];
      c1 = sigmoidf_(gf) * c1 + sigmoidf_(gi) * tanhf(gg);
      h1s[ar][aj] = sigmoidf_(go) * tanhf(c1);
    }
    __syncthreads();

    // ---------------- cell 2 gates: K = 256 (h1_new, h2) ----------------
    {
      float a0 = fmaf(xw2, x0, bs2);
      float a1 = fmaf(xw2, x1, bs2);
      #pragma unroll
      for (int kc = 0; kc < HH; kc += 8) {
        float p0[8], p1[8], q0[8], q1[8];
        LOAD8(p0, &h1s[0][kc]);
        LOAD8(p1, &h1s[1][kc]);
        LOAD8(q0, &h2s[0][kc]);
        LOAD8(q1, &h2s[1][kc]);
        #pragma unroll
        for (int j = 0; j < 8; ++j) {
          const float wa = W2a[(kc + j) << 9];
          const float wb = W2b[(kc + j) << 9];
          a0 = fmaf(wa, p0[j], fmaf(wb, q0[j], a0));
          a1 = fmaf(wa, p1[j], fmaf(wb, q1[j], a1));
        }
      }
      gs[0][tid] = a0;
      gs[1][tid] = a1;
    }
    __syncthreads();
    if (tid < ROWS * HH) {
      const float gi = gs[ar][aj];
      const float gf = gs[ar][aj + HH];
      const float gg = gs[ar][aj + 2 * HH];
      const float go = gs[ar][aj + 3 * HH];
      c2 = sigmoidf_(gf) * c2 + sigmoidf_(gi) * tanhf(gg);
      h2s[ar][aj] = sigmoidf_(go) * tanhf(c2);
    }
    __syncthreads();

    // ---------------- cell 3 gates: K = 384 (h1_new, h2_new, h3) ----------------
    {
      float a0 = fmaf(xw3, x0, bs3);
      float a1 = fmaf(xw3, x1, bs3);
      #pragma unroll
      for (int kc = 0; kc < HH; kc += 8) {
        float p0[8], p1[8], q0[8], q1[8], s0[8], s1[8];
        LOAD8(p0, &h1s[0][kc]);
        LOAD8(p1, &h1s[1][kc]);
        LOAD8(q0, &h2s[0][kc]);
        LOAD8(q1, &h2s[1][kc]);
        LOAD8(s0, &h3s[0][kc]);
        LOAD8(s1, &h3s[1][kc]);
        #pragma unroll
        for (int j = 0; j < 8; ++j) {
          const float wa = W3a[(kc + j) << 9];
          const float wb = W3b[(kc + j) << 9];
          const float wc = W3c[(kc + j) << 9];
          a0 = fmaf(wa, p0[j], fmaf(wb, q0[j], fmaf(wc, s0[j], a0)));
          a1 = fmaf(wa, p1[j], fmaf(wb, q1[j], fmaf(wc, s1[j], a1)));
        }
      }
      gs[0][tid] = a0;
      gs[1][tid] = a1;
    }
    __syncthreads();
    if (tid < ROWS * HH) {
      const float gi = gs[ar][aj];
      const float gf = gs[ar][aj + HH];
      const float gg = gs[ar][aj + 2 * HH];
      const float go = gs[ar][aj + 3 * HH];
      c3 = sigmoidf_(gf) * c3 + sigmoidf_(gi) * tanhf(gg);
      h3s[ar][aj] = sigmoidf_(go) * tanhf(c3);
    }
    __syncthreads();

    // ---------------- linear head + next-x ----------------
    if (wid < ROWS) {
      const int r = wid;
      float acc = 0.f;
      #pragma unroll
      for (int j0 = 0; j0 < HH; j0 += 64) {
        const int j = j0 + lane;
        acc += wl[1 + j] * h1s[r][j]
             + wl[1 + HH + j] * h2s[r][j]
             + wl[1 + 2 * HH + j] * h3s[r][j];
      }
      #pragma unroll
      for (int off = 32; off > 0; off >>= 1)
        acc += __shfl_down(acc, off, 64);
      if (lane == 0) {
        const float o = acc + fmaf(wl[0], xs[r], wl[3 * HH + 1]);
        out[(size_t)(r0 + r) * TT + t] = o;
        xs[r] = (t + 1 < TSEQ) ? x[(r0 + r) * TSEQ + (t + 1)] : o;
      }
    }

    // ---------------- phase-lock barrier (performance only, no data) -----
    if (tid == 0) {
      __hip_atomic_fetch_add(bar, 1u, __ATOMIC_RELAXED, __HIP_MEMORY_SCOPE_AGENT);
      const unsigned int target = (unsigned int)(t + 1) * NWG;
      // Poll with an RMW so the read executes at the coherence point
      // (no stale cross-XCD L2 copy can be served -> no deadlock).
      while (__hip_atomic_fetch_add(bar, 0u, __ATOMIC_RELAXED,
                                    __HIP_MEMORY_SCOPE_AGENT) < target) {
        __builtin_amdgcn_s_sleep(8);
      }
    }
    __syncthreads();
  }
}

extern "C" void kernel_launch(void* const* d_in, const int* in_sizes, int n_in,
                              void* d_out, int out_size, void* d_ws, size_t ws_size,
                              hipStream_t stream) {
  const float* x    = (const float*)d_in[0];
  const float* Wih1 = (const float*)d_in[1];
  const float* Whh1 = (const float*)d_in[2];
  const float* bih1 = (const float*)d_in[3];
  const float* bhh1 = (const float*)d_in[4];
  const float* Wih2 = (const float*)d_in[5];
  const float* Whh2 = (const float*)d_in[6];
  const float* bih2 = (const float*)d_in[7];
  const float* bhh2 = (const float*)d_in[8];
  const float* Wih3 = (const float*)d_in[9];
  const float* Whh3 = (const float*)d_in[10];
  const float* bih3 = (const float*)d_in[11];
  const float* bhh3 = (const float*)d_in[12];
  const float* Wlin = (const float*)d_in[13];
  const float* blin = (const float*)d_in[14];
  float* ws = (float*)d_ws;
  float* out = (float*)d_out;
  unsigned int* bar = (unsigned int*)(ws + WOFF_BAR);

  prep_kernel<<<(WS_FLOATS + 255) / 256, 256, 0, stream>>>(
      Wih1, Whh1, bih1, bhh1, Wih2, Whh2, bih2, bhh2,
      Wih3, Whh3, bih3, bhh3, ws);
  lstm_kernel<<<NWG, 512, 0, stream>>>(x, Wlin, blin, ws, bar, out);
}

// Round 3
// 23667.873 us; speedup vs baseline: 3.0286x; 3.0286x over previous
//
#include <hip/hip_runtime.h>
#include <math.h>

// DenseLSTMForecast: B=256, T=1024, H=128, FUTURE=32.
// 128 persistent WGs x 512 threads, each WG owns 2 batch rows for all 1056
// steps (row-local autoregressive feedback -> zero inter-WG communication).
//
// R3 change: fp16 weights + fp16 h-state + v_dot2_f32_f16 (fp32 accumulate).
// R1/R2 counters proved the fp32 design is stuck in a full-miss L2 equilibrium:
// FETCH = 6 plane-uses/XCD/step = 9.2 MB/step/XCD inflow > 4 MB L2, so no line
// survives to its next-step reuse (phase-locking changed nothing: FETCH was
// bit-identical). fp16 halves the set to 768 KB/step/XCD full-miss inflow,
// which is far below L2 capacity -> the miss equilibrium collapses and weights
// become L2-resident. dot2 also halves VALU and LDS-read work.
// Weight quantization err 2^-12 rel (weights in +-0.088, fp16-exact range).

#define TSEQ 1024
#define HH   128
#define TT   1056          // T + FUTURE
#define G4   512           // 4*H gate columns
#define ROWS 2
#define NWG  128

// ws layout (dword units):
//   6 planes of packed-fp16 weights, 32768 dwords (128 KB) each:
//     plane[k8][g][q]: k8=k/8 (16), g=gate col (512), q=pair-in-group (4)
//     dword = fp16(w[k8*8+2q, g]) | fp16(w[k8*8+2q+1, g]) << 16
//   planes: 0:W_hh1  1:W_ih2[:,1:129]  2:W_hh2  3:W_ih3[:,1:129]
//           4:W_ih3[:,129:257]  5:W_hh3
//   then fp32 scalars: xw1,xw2,xw3,bs1,bs2,bs3 (512 each)
#define PLANE_DW  (6 * 32768)
#define WOFF_SCAL PLANE_DW
#define WS_DWORDS (PLANE_DW + 3072)

typedef _Float16 h2t __attribute__((ext_vector_type(2)));
typedef _Float16 h8t __attribute__((ext_vector_type(8)));

__device__ __forceinline__ float sigmoidf_(float v) {
  return 1.0f / (1.0f + expf(-v));
}

// acc += dot(8 fp16 weights packed in uint4, 8 fp16 h values), fp32 accumulate
__device__ __forceinline__ float dot8(uint4 wu, h8t h, float acc) {
  h2t w0 = __builtin_bit_cast(h2t, wu.x);
  h2t w1 = __builtin_bit_cast(h2t, wu.y);
  h2t w2 = __builtin_bit_cast(h2t, wu.z);
  h2t w3 = __builtin_bit_cast(h2t, wu.w);
  h2t p0 = {h[0], h[1]}, p1 = {h[2], h[3]}, p2 = {h[4], h[5]}, p3 = {h[6], h[7]};
  acc = __builtin_amdgcn_fdot2(w0, p0, acc, false);
  acc = __builtin_amdgcn_fdot2(w1, p1, acc, false);
  acc = __builtin_amdgcn_fdot2(w2, p2, acc, false);
  acc = __builtin_amdgcn_fdot2(w3, p3, acc, false);
  return acc;
}

__global__ void prep_kernel(const float* __restrict__ Wih1, const float* __restrict__ Whh1,
                            const float* __restrict__ bih1, const float* __restrict__ bhh1,
                            const float* __restrict__ Wih2, const float* __restrict__ Whh2,
                            const float* __restrict__ bih2, const float* __restrict__ bhh2,
                            const float* __restrict__ Wih3, const float* __restrict__ Whh3,
                            const float* __restrict__ bih3, const float* __restrict__ bhh3,
                            float* __restrict__ ws) {
  int idx = blockIdx.x * 256 + threadIdx.x;
  if (idx < PLANE_DW) {
    int p = idx >> 15;           // plane (32768 dwords each)
    int rem = idx & 32767;
    int k8 = rem >> 11;          // 2048 dwords per k8 group
    int rem2 = rem & 2047;
    int g = rem2 >> 2;           // gate column
    int q = rem2 & 3;
    int k = k8 * 8 + q * 2;      // even k
    float v0, v1;
    switch (p) {
      case 0:  v0 = Whh1[g * HH + k];        v1 = Whh1[g * HH + k + 1];        break;
      case 1:  v0 = Wih2[g * 129 + 1 + k];   v1 = Wih2[g * 129 + 2 + k];       break;
      case 2:  v0 = Whh2[g * HH + k];        v1 = Whh2[g * HH + k + 1];        break;
      case 3:  v0 = Wih3[g * 257 + 1 + k];   v1 = Wih3[g * 257 + 2 + k];       break;
      case 4:  v0 = Wih3[g * 257 + 129 + k]; v1 = Wih3[g * 257 + 130 + k];     break;
      default: v0 = Whh3[g * HH + k];        v1 = Whh3[g * HH + k + 1];        break;
    }
    unsigned short b0 = __builtin_bit_cast(unsigned short, (_Float16)v0);
    unsigned short b1 = __builtin_bit_cast(unsigned short, (_Float16)v1);
    ((unsigned int*)ws)[idx] = (unsigned int)b0 | ((unsigned int)b1 << 16);
  } else if (idx < WS_DWORDS) {
    int r = idx - WOFF_SCAL;
    float v;
    if      (r < 512)  v = Wih1[r];                        // x column, cell1
    else if (r < 1024) v = Wih2[(r - 512) * 129];          // x column, cell2
    else if (r < 1536) v = Wih3[(r - 1024) * 257];         // x column, cell3
    else if (r < 2048) v = bih1[r - 1536] + bhh1[r - 1536];
    else if (r < 2560) v = bih2[r - 2048] + bhh2[r - 2048];
    else               v = bih3[r - 2560] + bhh3[r - 2560];
    ws[idx] = v;
  }
}

__global__ __launch_bounds__(512, 1)
void lstm_kernel(const float* __restrict__ x,
                 const float* __restrict__ Wlin,
                 const float* __restrict__ blin,
                 const float* __restrict__ ws,
                 float* __restrict__ out) {
  __shared__ __align__(16) _Float16 h1s[ROWS][HH];
  __shared__ __align__(16) _Float16 h2s[ROWS][HH];
  __shared__ __align__(16) _Float16 h3s[ROWS][HH];
  __shared__ float gs[ROWS][G4];
  __shared__ float xs[ROWS];
  __shared__ float wl[3 * HH + 2];   // [0]=x coef, [1..384]=h coefs, [385]=b_lin

  const int tid = threadIdx.x;
  const int r0 = blockIdx.x * ROWS;

  for (int i = tid; i < ROWS * HH; i += 512) {
    (&h1s[0][0])[i] = (_Float16)0.f;
    (&h2s[0][0])[i] = (_Float16)0.f;
    (&h3s[0][0])[i] = (_Float16)0.f;
  }
  for (int i = tid; i < 3 * HH + 2; i += 512)
    wl[i] = (i < 3 * HH + 1) ? Wlin[i] : blin[0];
  if (tid < ROWS) xs[tid] = x[(r0 + tid) * TSEQ];
  __syncthreads();

  const uint4* __restrict__ wsu4 = (const uint4*)ws;   // 8192 uint4 per plane
  const uint4* __restrict__ W1  = wsu4 + 0 * 8192 + tid;
  const uint4* __restrict__ W2a = wsu4 + 1 * 8192 + tid;
  const uint4* __restrict__ W2b = wsu4 + 2 * 8192 + tid;
  const uint4* __restrict__ W3a = wsu4 + 3 * 8192 + tid;
  const uint4* __restrict__ W3b = wsu4 + 4 * 8192 + tid;
  const uint4* __restrict__ W3c = wsu4 + 5 * 8192 + tid;
  const float xw1 = ws[WOFF_SCAL + tid];
  const float xw2 = ws[WOFF_SCAL + 512 + tid];
  const float xw3 = ws[WOFF_SCAL + 1024 + tid];
  const float bs1 = ws[WOFF_SCAL + 1536 + tid];
  const float bs2 = ws[WOFF_SCAL + 2048 + tid];
  const float bs3 = ws[WOFF_SCAL + 2560 + tid];

  float c1 = 0.f, c2 = 0.f, c3 = 0.f;          // used by tid < 256
  const int ar = tid >> 7, aj = tid & (HH - 1);
  const int wid = tid >> 6, lane = tid & 63;

  for (int t = 0; t < TT; ++t) {
    const float x0 = xs[0];
    const float x1 = xs[1];

    // ---------------- cell 1 gates: K = 128 (h1) ----------------
    {
      float a0 = fmaf(xw1, x0, bs1);
      float a1 = fmaf(xw1, x1, bs1);
      #pragma unroll
      for (int k8 = 0; k8 < 16; ++k8) {
        const uint4 wu = W1[k8 << 9];
        const h8t ha = *(const h8t*)&h1s[0][k8 * 8];
        const h8t hb = *(const h8t*)&h1s[1][k8 * 8];
        a0 = dot8(wu, ha, a0);
        a1 = dot8(wu, hb, a1);
      }
      gs[0][tid] = a0;
      gs[1][tid] = a1;
    }
    __syncthreads();
    if (tid < ROWS * HH) {
      const float gi = gs[ar][aj];
      const float gf = gs[ar][aj + HH];
      const float gg = gs[ar][aj + 2 * HH];
      const float go = gs[ar][aj + 3 * HH];
      c1 = sigmoidf_(gf) * c1 + sigmoidf_(gi) * tanhf(gg);
      h1s[ar][aj] = (_Float16)(sigmoidf_(go) * tanhf(c1));
    }
    __syncthreads();

    // ---------------- cell 2 gates: K = 256 (h1_new, h2) ----------------
    {
      float a0 = fmaf(xw2, x0, bs2);
      float a1 = fmaf(xw2, x1, bs2);
      #pragma unroll
      for (int k8 = 0; k8 < 16; ++k8) {
        const uint4 wa = W2a[k8 << 9];
        const uint4 wb = W2b[k8 << 9];
        const h8t p0 = *(const h8t*)&h1s[0][k8 * 8];
        const h8t p1 = *(const h8t*)&h1s[1][k8 * 8];
        const h8t q0 = *(const h8t*)&h2s[0][k8 * 8];
        const h8t q1 = *(const h8t*)&h2s[1][k8 * 8];
        a0 = dot8(wa, p0, a0);
        a1 = dot8(wa, p1, a1);
        a0 = dot8(wb, q0, a0);
        a1 = dot8(wb, q1, a1);
      }
      gs[0][tid] = a0;
      gs[1][tid] = a1;
    }
    __syncthreads();
    if (tid < ROWS * HH) {
      const float gi = gs[ar][aj];
      const float gf = gs[ar][aj + HH];
      const float gg = gs[ar][aj + 2 * HH];
      const float go = gs[ar][aj + 3 * HH];
      c2 = sigmoidf_(gf) * c2 + sigmoidf_(gi) * tanhf(gg);
      h2s[ar][aj] = (_Float16)(sigmoidf_(go) * tanhf(c2));
    }
    __syncthreads();

    // ---------------- cell 3 gates: K = 384 (h1_new, h2_new, h3) --------
    {
      float a0 = fmaf(xw3, x0, bs3);
      float a1 = fmaf(xw3, x1, bs3);
      #pragma unroll
      for (int k8 = 0; k8 < 16; ++k8) {
        const uint4 wa = W3a[k8 << 9];
        const uint4 wb = W3b[k8 << 9];
        const uint4 wc = W3c[k8 << 9];
        const h8t p0 = *(const h8t*)&h1s[0][k8 * 8];
        const h8t p1 = *(const h8t*)&h1s[1][k8 * 8];
        const h8t q0 = *(const h8t*)&h2s[0][k8 * 8];
        const h8t q1 = *(const h8t*)&h2s[1][k8 * 8];
        const h8t s0 = *(const h8t*)&h3s[0][k8 * 8];
        const h8t s1 = *(const h8t*)&h3s[1][k8 * 8];
        a0 = dot8(wa, p0, a0);
        a1 = dot8(wa, p1, a1);
        a0 = dot8(wb, q0, a0);
        a1 = dot8(wb, q1, a1);
        a0 = dot8(wc, s0, a0);
        a1 = dot8(wc, s1, a1);
      }
      gs[0][tid] = a0;
      gs[1][tid] = a1;
    }
    __syncthreads();
    if (tid < ROWS * HH) {
      const float gi = gs[ar][aj];
      const float gf = gs[ar][aj + HH];
      const float gg = gs[ar][aj + 2 * HH];
      const float go = gs[ar][aj + 3 * HH];
      c3 = sigmoidf_(gf) * c3 + sigmoidf_(gi) * tanhf(gg);
      h3s[ar][aj] = (_Float16)(sigmoidf_(go) * tanhf(c3));
    }
    __syncthreads();

    // ---------------- linear head + next-x ----------------
    if (wid < ROWS) {
      const int r = wid;
      float acc = 0.f;
      #pragma unroll
      for (int j0 = 0; j0 < HH; j0 += 64) {
        const int j = j0 + lane;
        acc += wl[1 + j] * (float)h1s[r][j]
             + wl[1 + HH + j] * (float)h2s[r][j]
             + wl[1 + 2 * HH + j] * (float)h3s[r][j];
      }
      #pragma unroll
      for (int off = 32; off > 0; off >>= 1)
        acc += __shfl_down(acc, off, 64);
      if (lane == 0) {
        const float o = acc + fmaf(wl[0], xs[r], wl[3 * HH + 1]);
        out[(size_t)(r0 + r) * TT + t] = o;
        xs[r] = (t + 1 < TSEQ) ? x[(r0 + r) * TSEQ + (t + 1)] : o;
      }
    }
    __syncthreads();
  }
}

extern "C" void kernel_launch(void* const* d_in, const int* in_sizes, int n_in,
                              void* d_out, int out_size, void* d_ws, size_t ws_size,
                              hipStream_t stream) {
  const float* x    = (const float*)d_in[0];
  const float* Wih1 = (const float*)d_in[1];
  const float* Whh1 = (const float*)d_in[2];
  const float* bih1 = (const float*)d_in[3];
  const float* bhh1 = (const float*)d_in[4];
  const float* Wih2 = (const float*)d_in[5];
  const float* Whh2 = (const float*)d_in[6];
  const float* bih2 = (const float*)d_in[7];
  const float* bhh2 = (const float*)d_in[8];
  const float* Wih3 = (const float*)d_in[9];
  const float* Whh3 = (const float*)d_in[10];
  const float* bih3 = (const float*)d_in[11];
  const float* bhh3 = (const float*)d_in[12];
  const float* Wlin = (const float*)d_in[13];
  const float* blin = (const float*)d_in[14];
  float* ws = (float*)d_ws;
  float* out = (float*)d_out;

  prep_kernel<<<(WS_DWORDS + 255) / 256, 256, 0, stream>>>(
      Wih1, Whh1, bih1, bhh1, Wih2, Whh2, bih2, bhh2,
      Wih3, Whh3, bih3, bhh3, ws);
  lstm_kernel<<<NWG, 512, 0, stream>>>(x, Wlin, blin, ws, out);
}